// Round 10
// baseline (40.652 us; speedup 1.0000x reference)
//
#include <hip/hip_runtime.h>
#include <hip/hip_bf16.h>

#define NND 2000
#define KNB 16
#define CS 128
#define CZ 64
#define NE (NND*KNB)

typedef __attribute__((ext_vector_type(8))) short short8;
typedef __attribute__((ext_vector_type(4))) float f32x4;
typedef __attribute__((ext_vector_type(4))) unsigned int uint4v;

// hardware bf16 convert (compiler emits v_cvt_pk_bf16_f32; RNE)
__device__ __forceinline__ unsigned int pk2(float a, float b) {
  __hip_bfloat162 h = __float22bfloat162_rn(make_float2(a, b));
  unsigned int u;
  __builtin_memcpy(&u, &h, 4);
  return u;
}
__device__ __forceinline__ unsigned short bfc(float f) {
  __hip_bfloat16 h = __float2bfloat16(f);
  unsigned short u;
  __builtin_memcpy(&u, &h, 2);
  return u;
}

__device__ __forceinline__ float fexp2(float x) {
#if __has_builtin(__builtin_amdgcn_exp2f)
  return __builtin_amdgcn_exp2f(x);
#else
  return __expf(0.6931471805599453f * x);
#endif
}

// ---------------------------------------------------------------------------
// Precompute (r5 form + NEGATED logits):
//   blocks [0,500): g1 = -(nf@wg1 + b_gate)*log2e, g2 = -(nf@wg2)*log2e
//   block 500: wave0 bias2; wave1 wdbF; wave2 wedF; wave3 woF (bf16 frags).
// ---------------------------------------------------------------------------
__global__ __launch_bounds__(256) void precompute_kernel(
    const float* __restrict__ nf,
    const float* __restrict__ w_gate, const float* __restrict__ b_gate,
    const float* __restrict__ ln_b, const float* __restrict__ w_out,
    const float* __restrict__ b_out,
    const float* __restrict__ w_db, const float* __restrict__ w_edge,
    const float* __restrict__ ln_g,
    float* __restrict__ g1, float* __restrict__ g2, float* __restrict__ bias2,
    unsigned short* __restrict__ wdbF, unsigned short* __restrict__ wedF,
    unsigned short* __restrict__ woF)
{
  const int p = threadIdx.x;
  const int lane = p & 63;
  const int wv   = p >> 6;
  const int b    = blockIdx.x;
  if (b < NND/4) {
    const int v = b*4 + wv;
    const float* nrow = nf + v*CS;
    float a10=0.f,a11=0.f,a12=0.f,a13=0.f;
    float a20=0.f,a21=0.f,a22=0.f,a23=0.f;
    #pragma unroll
    for (int cc = 0; cc < CS; cc += 4) {
      const f32x4 x = *(const f32x4*)&nrow[cc];
      a10 = fmaf(x[0], w_gate[(cc+0)*CZ + lane], a10);
      a11 = fmaf(x[1], w_gate[(cc+1)*CZ + lane], a11);
      a12 = fmaf(x[2], w_gate[(cc+2)*CZ + lane], a12);
      a13 = fmaf(x[3], w_gate[(cc+3)*CZ + lane], a13);
      a20 = fmaf(x[0], w_gate[(CS+cc+0)*CZ + lane], a20);
      a21 = fmaf(x[1], w_gate[(CS+cc+1)*CZ + lane], a21);
      a22 = fmaf(x[2], w_gate[(CS+cc+2)*CZ + lane], a22);
      a23 = fmaf(x[3], w_gate[(CS+cc+3)*CZ + lane], a23);
    }
    const float a1 = b_gate[lane] + ((a10+a11)+(a12+a13));
    const float a2 = (a20+a21)+(a22+a23);
    g1[v*CZ + lane] = a1 * -1.4426950408889634f;   // NEGATED, log2e folded
    g2[v*CZ + lane] = a2 * -1.4426950408889634f;
  } else {
    if (wv == 0) {
      float a = b_out[lane];
      #pragma unroll
      for (int cc = 0; cc < CZ; ++cc)
        a = fmaf(ln_b[cc], w_out[cc*CZ + lane], a);
      bias2[lane] = a;
    } else if (wv == 1) {
      for (int e = lane; e < 4096; e += 64) {
        const int entry = e >> 3, t = e & 7;
        const int l2 = entry & 63, sn = entry >> 6;
        const int s = sn >> 2, nt = sn & 3;
        const int q2 = l2 >> 4, c2 = l2 & 15;
        wdbF[e] = bfc(w_db[(32*s + 8*q2 + t)*CZ + 16*nt + c2]);
      }
    } else if (wv == 2) {
      for (int e = lane; e < 4096; e += 64) {
        const int entry = e >> 3, t = e & 7;
        const int p2 = entry & 255, s = entry >> 8;
        const int q2 = (p2 >> 4) & 3, c2 = p2 & 15;
        wedF[e] = bfc(w_edge[(32*s + 8*q2 + t)*CZ + 16*(p2 >> 6) + c2]);
      }
    } else {
      for (int e = lane; e < 4096; e += 64) {
        const int entry = e >> 3, t = e & 7;
        const int p2 = entry & 255, s = entry >> 8;
        const int q2 = (p2 >> 4) & 3, c2 = p2 & 15;
        const int k = 32*s + 8*q2 + t;
        woF[e] = bfc(w_out[k*CZ + 16*(p2 >> 6) + c2] * ln_g[k]);
      }
    }
  }
}

// ---------------------------------------------------------------------------
// Fused main kernel: one block (4 waves) per node, ONE barrier (xh only).
//   kf redundant per wave in registers (C-frag == gate layout); g1/g2 via
//   hoisted row pointers (imm-offset folded loads); minimal gate chain.
// Frag maps: A row=l&15,k=(l>>4)*8+t; B col=l&15,k=(l>>4)*8+t;
//            C col=l&15, row=4*(l>>4)+reg.
// ---------------------------------------------------------------------------
__global__ __launch_bounds__(256, 3) void fused_main_kernel(
    const float* __restrict__ trans, const int* __restrict__ eidx,
    const float* __restrict__ g1, const float* __restrict__ g2,
    const float* __restrict__ ef, const float* __restrict__ b_edge,
    const float* __restrict__ b_db, const float* __restrict__ bias2,
    const unsigned short* __restrict__ wdbF,
    const unsigned short* __restrict__ wedF,
    const unsigned short* __restrict__ woF,
    float* __restrict__ out)
{
  __shared__ unsigned short xh[KNB][72];     // xhat bf16 (transpose for MFMA2)

  const int n = blockIdx.x;
  const int p = threadIdx.x;
  const int w = p >> 6, l = p & 63, q = l >> 4, c = l & 15;
  const int base = n*KNB;

  // ---- vectorized index loads ------------------------------------------
  const int4 eq = *(const int4*)&eidx[base + 4*q];   // rows i = 4q+r
  const int4 ej = *(const int4*)&eidx[base + 4*w];   // rows j = 4w+m
  const int  e_c = eidx[base + c];                   // t_i

  // hoisted gather pointers (imm-offset folds 16*nt*4 bytes)
  const float* g1p0 = g1 + eq.x*CZ + c;
  const float* g1p1 = g1 + eq.y*CZ + c;
  const float* g1p2 = g1 + eq.z*CZ + c;
  const float* g1p3 = g1 + eq.w*CZ + c;
  const float* g2p0 = g2 + ej.x*CZ + c;
  const float* g2p1 = g2 + ej.y*CZ + c;
  const float* g2p2 = g2 + ej.z*CZ + c;
  const float* g2p3 = g2 + ej.w*CZ + c;

  const float tc0 = trans[e_c*3+0], tc1 = trans[e_c*3+1], tc2 = trans[e_c*3+2];
  float tj[4][3];
  {
    const int js[4] = {ej.x, ej.y, ej.z, ej.w};
    #pragma unroll
    for (int m = 0; m < 4; ++m) {
      tj[m][0] = trans[js[m]*3+0];
      tj[m][1] = trans[js[m]*3+1];
      tj[m][2] = trans[js[m]*3+2];
    }
  }

  // ef A-frags: row = edge i=c, k = 32s+8q+t
  short8 afe[2];
  #pragma unroll
  for (int s = 0; s < 2; ++s) {
    const float* src = &ef[(base + c)*CZ + 32*s + 8*q];
    const f32x4 x0 = *(const f32x4*)src;
    const f32x4 x1 = *(const f32x4*)(src + 4);
    uint4v u;
    u[0] = pk2(x0[0], x0[1]);
    u[1] = pk2(x0[2], x0[3]);
    u[2] = pk2(x1[0], x1[1]);
    u[3] = pk2(x1[2], x1[3]);
    short8 v;
    __builtin_memcpy(&v, &u, 16);
    afe[s] = v;
  }

  // wdb B-frags resident for the whole nt loop
  short8 bfr[2][4];
  #pragma unroll
  for (int s = 0; s < 2; ++s)
    #pragma unroll
    for (int nt = 0; nt < 4; ++nt)
      bfr[s][nt] = *(const short8*)&wdbF[((s*4 + nt)*64 + l)*8];

  // ---- kf = ef @ w_edge + b_edge, all 4 col-blocks in registers --------
  f32x4 accK[4];
  #pragma unroll
  for (int nt = 0; nt < 4; ++nt) {
    const float be = b_edge[16*nt + c];
    accK[nt] = (f32x4){be, be, be, be};
  }
  #pragma unroll
  for (int s = 0; s < 2; ++s)
    #pragma unroll
    for (int nt = 0; nt < 4; ++nt) {
      const short8 wed = *(const short8*)&wedF[(s*256 + nt*64 + l)*8];
      accK[nt] = __builtin_amdgcn_mfma_f32_16x16x32_bf16(afe[s], wed, accK[nt], 0, 0, 0);
    }

  // ---- distances + rbf A-frags (pair i=c, j=4w+m) ----------------------
  const float STEP = 1.2201878439258035f;    // (20/63)*3.2*sqrt(log2e)
  float dsc[4];
  #pragma unroll
  for (int m = 0; m < 4; ++m) {
    const float dx = tc0 - tj[m][0] + 1e-8f;
    const float dy = tc1 - tj[m][1] + 1e-8f;
    const float dz = tc2 - tj[m][2] + 1e-8f;
    dsc[m] = sqrtf(fmaf(dx,dx, fmaf(dy,dy, dz*dz))) * 3.8435917081166394f;
  }
  const float qoff = (float)(8*q) * STEP;
  short8 af[2][4];
  #pragma unroll
  for (int s = 0; s < 2; ++s) {
    const float soff = qoff + (float)(32*s) * STEP;
    #pragma unroll
    for (int m = 0; m < 4; ++m) {
      const float bse = dsc[m] - soff;
      uint4v u;
      #pragma unroll
      for (int t = 0; t < 4; ++t) {
        const float ua = fmaf(-STEP, (float)(2*t),   bse);
        const float ub = fmaf(-STEP, (float)(2*t+1), bse);
        u[t] = pk2(fexp2(-ua*ua), fexp2(-ub*ub));
      }
      short8 v;
      __builtin_memcpy(&v, &u, 16);
      af[s][m] = v;
    }
  }

  // ---- per-nt: MFMA1 (C-init = b_db) + gate + i-reduce -----------------
  float upd[4][4];   // [m][nt]
  #pragma unroll
  for (int nt = 0; nt < 4; ++nt) {
    const float bdbn = b_db[16*nt + c];
    f32x4 accD[4];
    #pragma unroll
    for (int m = 0; m < 4; ++m) accD[m] = (f32x4){bdbn, bdbn, bdbn, bdbn};
    #pragma unroll
    for (int s = 0; s < 2; ++s)
      #pragma unroll
      for (int m = 0; m < 4; ++m)
        accD[m] = __builtin_amdgcn_mfma_f32_16x16x32_bf16(af[s][m], bfr[s][nt], accD[m], 0, 0, 0);

    // 1-inst gathers (imm-offset): negated logits
    const float g1v0 = g1p0[16*nt], g1v1 = g1p1[16*nt];
    const float g1v2 = g1p2[16*nt], g1v3 = g1p3[16*nt];
    const float g2v0 = g2p0[16*nt], g2v1 = g2p1[16*nt];
    const float g2v2 = g2p2[16*nt], g2v3 = g2p3[16*nt];
    const float g2v[4] = {g2v0, g2v1, g2v2, g2v3};
    const float g1v[4] = {g1v0, g1v1, g1v2, g1v3};

    #pragma unroll
    for (int m = 0; m < 4; ++m) {
      float ss = 0.f;
      #pragma unroll
      for (int r = 0; r < 4; ++r) {
        // gate = 1/(1 + exp2(g1n + g2n)), logits pre-negated
        const float gate = __builtin_amdgcn_rcpf(1.0f + fexp2(g1v[r] + g2v[m]));
        ss = fmaf(gate * accD[m][r], accK[nt][r], ss);
      }
      ss += __shfl_xor(ss, 16);
      ss += __shfl_xor(ss, 32);
      upd[m][nt] = ss;
    }
  }

  // proj B-frags (hide under LN)
  short8 wb[2];
  #pragma unroll
  for (int s = 0; s < 2; ++s)
    wb[s] = *(const short8*)&woF[(s*256 + p)*8];

  // ---- LayerNorm: group q owns row j = 4w+q ----------------------------
  {
    float v[4];
    #pragma unroll
    for (int nt = 0; nt < 4; ++nt)
      v[nt] = (q == 0) ? upd[0][nt] : (q == 1) ? upd[1][nt]
            : (q == 2) ? upd[2][nt] : upd[3][nt];
    float s1 = (v[0] + v[1]) + (v[2] + v[3]);
    float s2 = fmaf(v[0],v[0], fmaf(v[1],v[1], fmaf(v[2],v[2], v[3]*v[3])));
    #pragma unroll
    for (int mk = 1; mk <= 8; mk <<= 1) {
      s1 += __shfl_xor(s1, mk);
      s2 += __shfl_xor(s2, mk);
    }
    const float mean = s1 * 0.015625f;
    const float var  = fmaf(s2, 0.015625f, -mean*mean);
    const float rstd = rsqrtf(var + 1e-5f);
    #pragma unroll
    for (int nt = 0; nt < 4; ++nt)
      xh[4*w + q][16*nt + c] = bfc((v[nt] - mean) * rstd);
  }
  __syncthreads();   // only barrier: xh transpose for MFMA2

  // ---- MFMA2: out = xhat @ (ln_g*w_out) + bias2 ------------------------
  f32x4 acc2 = {};
  #pragma unroll
  for (int s = 0; s < 2; ++s) {
    const short8 a2f = *(const short8*)&xh[c][q*8 + 32*s];
    acc2 = __builtin_amdgcn_mfma_f32_16x16x32_bf16(a2f, wb[s], acc2, 0, 0, 0);
  }
  const float bo = bias2[16*w + c];
  #pragma unroll
  for (int r = 0; r < 4; ++r)
    out[(base + 4*q + r)*CZ + 16*w + c] = acc2[r] + bo;
}

extern "C" void kernel_launch(void* const* d_in, const int* in_sizes, int n_in,
                              void* d_out, int out_size, void* d_ws, size_t ws_size,
                              hipStream_t stream)
{
  const float* nf     = (const float*)d_in[0];
  const float* trans  = (const float*)d_in[1];
  const float* ef     = (const float*)d_in[2];
  const int*   eidx   = (const int*)d_in[3];
  const float* w_gate = (const float*)d_in[4];
  const float* b_gate = (const float*)d_in[5];
  const float* w_db   = (const float*)d_in[6];
  const float* b_db   = (const float*)d_in[7];
  const float* w_edge = (const float*)d_in[8];
  const float* b_edge = (const float*)d_in[9];
  const float* ln_g   = (const float*)d_in[10];
  const float* ln_b   = (const float*)d_in[11];
  const float* w_out  = (const float*)d_in[12];
  const float* b_out  = (const float*)d_in[13];
  float* out = (float*)d_out;

  float* g1    = (float*)d_ws;                            // [2000][64] f32
  float* g2    = g1 + NND*CZ;                             // [2000][64] f32
  float* bias2 = g2 + NND*CZ;                             // [64] f32
  unsigned short* wdbF = (unsigned short*)(bias2 + CZ);   // 4096 bf16
  unsigned short* wedF = wdbF + 4096;                     // 4096 bf16
  unsigned short* woF  = wedF + 4096;                     // 4096 bf16

  precompute_kernel<<<NND/4 + 1, 256, 0, stream>>>(
      nf, w_gate, b_gate, ln_b, w_out, b_out, w_db, w_edge, ln_g,
      g1, g2, bias2, wdbF, wedF, woF);
  fused_main_kernel<<<NND, 256, 0, stream>>>(
      trans, eidx, g1, g2, ef, b_edge, b_db, bias2,
      wdbF, wedF, woF, out);
}

// Round 11
// 33.182 us; speedup vs baseline: 1.2251x; 1.2251x over previous
//
#include <hip/hip_runtime.h>

#define NND 2000
#define KNB 16
#define CS 128
#define CZ 64
#define NE (NND*KNB)

typedef __attribute__((ext_vector_type(8))) short short8;
typedef __attribute__((ext_vector_type(4))) float f32x4;
typedef __attribute__((ext_vector_type(2))) unsigned int uint2v;
typedef __attribute__((ext_vector_type(4))) unsigned int uint4v;

__device__ __forceinline__ unsigned short f2bf(float f) {
  unsigned int u = __float_as_uint(f);
  u += 0x7fffu + ((u >> 16) & 1u);      // RNE round to bf16
  return (unsigned short)(u >> 16);
}

__device__ __forceinline__ float fexp2(float x) {
#if __has_builtin(__builtin_amdgcn_exp2f)
  return __builtin_amdgcn_exp2f(x);
#else
  return __expf(0.6931471805599453f * x);
#endif
}

// ---------------------------------------------------------------------------
// Precompute:
//   blocks [0,500): per-node gate logits G1/G2. w_gate staged ONCE per block
//     into 64KB LDS (the old path re-read 128KB of L2 per wave: 256MB total).
//     FMA loop reads LDS row-broadcasts (2 lanes/bank = conflict-free).
//   block 500: wave0 bias2; wave1 wdbF; wave2 wedF; wave3 woF (bf16 frags).
// ---------------------------------------------------------------------------
__global__ __launch_bounds__(256) void precompute_kernel(
    const float* __restrict__ nf,
    const float* __restrict__ w_gate, const float* __restrict__ b_gate,
    const float* __restrict__ ln_b, const float* __restrict__ w_out,
    const float* __restrict__ b_out,
    const float* __restrict__ w_db, const float* __restrict__ w_edge,
    const float* __restrict__ ln_g,
    float* __restrict__ g1, float* __restrict__ g2, float* __restrict__ bias2,
    unsigned short* __restrict__ wdbF, unsigned short* __restrict__ wedF,
    unsigned short* __restrict__ woF)
{
  __shared__ float wl[2*CS][CZ];        // 64 KB: w_gate staged per block
  const int p = threadIdx.x;
  const int lane = p & 63;
  const int wv   = p >> 6;
  const int b    = blockIdx.x;
  if (b < NND/4) {
    // stage w_gate (coalesced f32x4 loads, conflict-free b128 LDS writes)
    #pragma unroll
    for (int t = 0; t < 16; ++t) {
      const int e = (p + 256*t) * 4;    // element offset 0..65532
      const f32x4 x = *(const f32x4*)&w_gate[e];
      *(f32x4*)&wl[e >> 6][e & 63] = x;
    }
    __syncthreads();

    const int v = b*4 + wv;
    const float* nrow = nf + v*CS;
    float a10=0.f,a11=0.f,a12=0.f,a13=0.f;
    float a20=0.f,a21=0.f,a22=0.f,a23=0.f;
    #pragma unroll
    for (int cc = 0; cc < CS; cc += 4) {
      const f32x4 x = *(const f32x4*)&nrow[cc];
      a10 = fmaf(x[0], wl[cc+0][lane], a10);
      a11 = fmaf(x[1], wl[cc+1][lane], a11);
      a12 = fmaf(x[2], wl[cc+2][lane], a12);
      a13 = fmaf(x[3], wl[cc+3][lane], a13);
      a20 = fmaf(x[0], wl[CS+cc+0][lane], a20);
      a21 = fmaf(x[1], wl[CS+cc+1][lane], a21);
      a22 = fmaf(x[2], wl[CS+cc+2][lane], a22);
      a23 = fmaf(x[3], wl[CS+cc+3][lane], a23);
    }
    const float a1 = b_gate[lane] + ((a10+a11)+(a12+a13));
    const float a2 = (a20+a21)+(a22+a23);
    g1[v*CZ + lane] = a1 * 1.4426950408889634f;   // log2e folded (exp2 gate)
    g2[v*CZ + lane] = a2 * 1.4426950408889634f;
  } else {
    if (wv == 0) {
      float a = b_out[lane];
      #pragma unroll
      for (int cc = 0; cc < CZ; ++cc)
        a = fmaf(ln_b[cc], w_out[cc*CZ + lane], a);
      bias2[lane] = a;
    } else if (wv == 1) {
      for (int e = lane; e < 4096; e += 64) {
        const int entry = e >> 3, t = e & 7;
        const int l2 = entry & 63, sn = entry >> 6;
        const int s = sn >> 2, nt = sn & 3;
        const int q2 = l2 >> 4, c2 = l2 & 15;
        wdbF[e] = f2bf(w_db[(32*s + 8*q2 + t)*CZ + 16*nt + c2]);
      }
    } else if (wv == 2) {
      for (int e = lane; e < 4096; e += 64) {
        const int entry = e >> 3, t = e & 7;
        const int p2 = entry & 255, s = entry >> 8;
        const int q2 = (p2 >> 4) & 3, c2 = p2 & 15;
        wedF[e] = f2bf(w_edge[(32*s + 8*q2 + t)*CZ + 16*(p2 >> 6) + c2]);
      }
    } else {
      for (int e = lane; e < 4096; e += 64) {
        const int entry = e >> 3, t = e & 7;
        const int p2 = entry & 255, s = entry >> 8;
        const int q2 = (p2 >> 4) & 3, c2 = p2 & 15;
        const int k = 32*s + 8*q2 + t;
        woF[e] = f2bf(w_out[k*CZ + 16*(p2 >> 6) + c2] * ln_g[k]);
      }
    }
  }
}

// ---------------------------------------------------------------------------
// Fused main kernel: VERBATIM the round-5 33.99us version. One block (4
// waves) per node, 3 barriers, front-loaded global traffic, bfr streamed
// per-nt to stay under 128 VGPRs.
// ---------------------------------------------------------------------------
__global__ __launch_bounds__(256, 4) void fused_main_kernel(
    const float* __restrict__ trans, const int* __restrict__ eidx,
    const float* __restrict__ g1, const float* __restrict__ g2,
    const float* __restrict__ ef, const float* __restrict__ b_edge,
    const float* __restrict__ b_db, const float* __restrict__ bias2,
    const unsigned short* __restrict__ wdbF,
    const unsigned short* __restrict__ wedF,
    const unsigned short* __restrict__ woF,
    float* __restrict__ out)
{
  __shared__ float G1l[KNB][68];
  __shared__ float G2l[KNB][68];
  __shared__ float kfl[KNB][68];
  __shared__ unsigned short xh[KNB][72];     // xhat bf16

  const int n = blockIdx.x;
  const int p = threadIdx.x;
  const int w = p >> 6;
  const int l = p & 63;
  const int q = l >> 4;
  const int c = l & 15;
  const int r16 = p >> 4, c4 = (p & 15) * 4;

  // ---- front-loaded global traffic (all independent of LDS/barriers) ----
  const int sr = eidx[n*KNB + r16];          // G-row gather index
  const int sc = eidx[n*KNB + c];            // t_i index
  int sj[4];
  #pragma unroll
  for (int m = 0; m < 4; ++m) sj[m] = eidx[n*KNB + 4*w + m];

  const f32x4 g1row = *(const f32x4*)&g1[sr*CZ + c4];
  const f32x4 g2row = *(const f32x4*)&g2[sr*CZ + c4];
  const f32x4 efrow = *(const f32x4*)&ef[(n*KNB + r16)*CZ + c4];

  const float tc0 = trans[sc*3+0], tc1 = trans[sc*3+1], tc2 = trans[sc*3+2];
  float tj[4][3];
  #pragma unroll
  for (int m = 0; m < 4; ++m) {
    tj[m][0] = trans[sj[m]*3+0];
    tj[m][1] = trans[sj[m]*3+1];
    tj[m][2] = trans[sj[m]*3+2];
  }

  short8 wed[2];
  #pragma unroll
  for (int s = 0; s < 2; ++s)
    wed[s] = *(const short8*)&wedF[(s*256 + p)*8];
  short8 bcur[2];
  #pragma unroll
  for (int s = 0; s < 2; ++s)
    bcur[s] = *(const short8*)&wdbF[(s*4*64 + l)*8];

  const float be = b_edge[16*w + c];
  const float bo = bias2[16*w + c];
  float bdb[4];
  #pragma unroll
  for (int nt = 0; nt < 4; ++nt) bdb[nt] = b_db[16*nt + c];

  // ---- register-only compute while loads land ----
  const float STEP = 1.2201878439258035f;
  float dsc[4];
  #pragma unroll
  for (int m = 0; m < 4; ++m) {
    const float dx = tc0 - tj[m][0] + 1e-8f;
    const float dy = tc1 - tj[m][1] + 1e-8f;
    const float dz = tc2 - tj[m][2] + 1e-8f;
    dsc[m] = sqrtf(fmaf(dx,dx, fmaf(dy,dy, dz*dz))) * 3.8435917081166394f;
  }
  const float qoff = (float)(8*q) * STEP;

  // rbf A-frags: af[s][m], row i=c, k = 32s+8q+t   (64 exp2)
  short8 af[2][4];
  #pragma unroll
  for (int s = 0; s < 2; ++s) {
    const float soff = qoff + (float)(32*s) * STEP;
    #pragma unroll
    for (int m = 0; m < 4; ++m) {
      const float base = dsc[m] - soff;
      short8 v;
      #pragma unroll
      for (int t = 0; t < 8; ++t) {
        const float u = fmaf(-STEP, (float)t, base);
        v[t] = (short)f2bf(fexp2(-u*u));
      }
      af[s][m] = v;
    }
  }

  { // stage ef tile bf16 + G rows (register -> LDS)
    uint2v pk;
    pk[0] = (unsigned int)f2bf(efrow[0]) | ((unsigned int)f2bf(efrow[1]) << 16);
    pk[1] = (unsigned int)f2bf(efrow[2]) | ((unsigned int)f2bf(efrow[3]) << 16);
    *(uint2v*)&xh[r16][c4] = pk;             // reuse xh as ef-tile buffer
    *(f32x4*)&G1l[r16][c4] = g1row;
    *(f32x4*)&G2l[r16][c4] = g2row;
  }
  __syncthreads();   // b1: ef tile (in xh), G1l, G2l visible

  { // MFMA0: kf tile; wave w owns cols 16w..16w+15
    f32x4 ak = {};
    #pragma unroll
    for (int s = 0; s < 2; ++s) {
      const short8 a0 = *(const short8*)&xh[c][q*8 + 32*s];
      ak = __builtin_amdgcn_mfma_f32_16x16x32_bf16(a0, wed[s], ak, 0, 0, 0);
    }
    #pragma unroll
    for (int r = 0; r < 4; ++r)
      kfl[4*q + r][16*w + c] = ak[r] + be;
  }
  __syncthreads();   // b2: kfl visible (xh free again)

  // ---- per-nt fused MFMA1 + gate + i-reduce (acc streamed, 16 regs) ----
  float upd[4][4];   // [m][nt]
  #pragma unroll
  for (int nt = 0; nt < 4; ++nt) {
    short8 bnext[2];
    if (nt < 3) {
      #pragma unroll
      for (int s = 0; s < 2; ++s)
        bnext[s] = *(const short8*)&wdbF[((s*4 + nt+1)*64 + l)*8];
    }
    float g1v[4], kfv[4];
    #pragma unroll
    for (int r = 0; r < 4; ++r) {
      g1v[r] = G1l[4*q + r][16*nt + c];
      kfv[r] = kfl[4*q + r][16*nt + c];
    }
    const float bdbn = bdb[nt];
    f32x4 acc[4] = {};
    #pragma unroll
    for (int s = 0; s < 2; ++s)
      #pragma unroll
      for (int m = 0; m < 4; ++m)
        acc[m] = __builtin_amdgcn_mfma_f32_16x16x32_bf16(af[s][m], bcur[s], acc[m], 0, 0, 0);

    #pragma unroll
    for (int m = 0; m < 4; ++m) {
      const float g2vm = G2l[4*w + m][16*nt + c];
      float ss = 0.f;
      #pragma unroll
      for (int r = 0; r < 4; ++r) {
        const float gate = __builtin_amdgcn_rcpf(1.0f + fexp2(-(g1v[r] + g2vm)));
        ss = fmaf(gate * (acc[m][r] + bdbn), kfv[r], ss);
      }
      ss += __shfl_xor(ss, 16);
      ss += __shfl_xor(ss, 32);
      upd[m][nt] = ss;
    }
    if (nt < 3) { bcur[0] = bnext[0]; bcur[1] = bnext[1]; }
  }

  // proj B-frags (hide under LN)
  short8 wb[2];
  #pragma unroll
  for (int s = 0; s < 2; ++s)
    wb[s] = *(const short8*)&woF[(s*256 + p)*8];

  // ---- LayerNorm: q-group q owns row j = 4w+q (no redundancy) ----------
  {
    float v[4];
    #pragma unroll
    for (int nt = 0; nt < 4; ++nt)
      v[nt] = (q == 0) ? upd[0][nt] : (q == 1) ? upd[1][nt]
            : (q == 2) ? upd[2][nt] : upd[3][nt];
    float s1 = (v[0] + v[1]) + (v[2] + v[3]);
    float s2 = fmaf(v[0],v[0], fmaf(v[1],v[1], fmaf(v[2],v[2], v[3]*v[3])));
    #pragma unroll
    for (int mk = 1; mk <= 8; mk <<= 1) {
      s1 += __shfl_xor(s1, mk);
      s2 += __shfl_xor(s2, mk);
    }
    const float mean = s1 * 0.015625f;
    const float var  = fmaf(s2, 0.015625f, -mean*mean);
    const float rstd = rsqrtf(var + 1e-5f);
    #pragma unroll
    for (int nt = 0; nt < 4; ++nt)
      xh[4*w + q][16*nt + c] = f2bf((v[nt] - mean) * rstd);
  }
  __syncthreads();   // b3: xh visible

  // ---- MFMA2: out = xhat @ (ln_g*w_out) + bias2 ------------------------
  f32x4 acc2 = {};
  #pragma unroll
  for (int s = 0; s < 2; ++s) {
    const short8 a2f = *(const short8*)&xh[c][q*8 + 32*s];
    acc2 = __builtin_amdgcn_mfma_f32_16x16x32_bf16(a2f, wb[s], acc2, 0, 0, 0);
  }
  #pragma unroll
  for (int r = 0; r < 4; ++r)
    out[(n*KNB + 4*q + r)*CZ + 16*w + c] = acc2[r] + bo;
}

extern "C" void kernel_launch(void* const* d_in, const int* in_sizes, int n_in,
                              void* d_out, int out_size, void* d_ws, size_t ws_size,
                              hipStream_t stream)
{
  const float* nf     = (const float*)d_in[0];
  const float* trans  = (const float*)d_in[1];
  const float* ef     = (const float*)d_in[2];
  const int*   eidx   = (const int*)d_in[3];
  const float* w_gate = (const float*)d_in[4];
  const float* b_gate = (const float*)d_in[5];
  const float* w_db   = (const float*)d_in[6];
  const float* b_db   = (const float*)d_in[7];
  const float* w_edge = (const float*)d_in[8];
  const float* b_edge = (const float*)d_in[9];
  const float* ln_g   = (const float*)d_in[10];
  const float* ln_b   = (const float*)d_in[11];
  const float* w_out  = (const float*)d_in[12];
  const float* b_out  = (const float*)d_in[13];
  float* out = (float*)d_out;

  float* g1    = (float*)d_ws;                            // [2000][64] f32
  float* g2    = g1 + NND*CZ;                             // [2000][64] f32
  float* bias2 = g2 + NND*CZ;                             // [64] f32
  unsigned short* wdbF = (unsigned short*)(bias2 + CZ);   // 4096 bf16
  unsigned short* wedF = wdbF + 4096;                     // 4096 bf16
  unsigned short* woF  = wedF + 4096;                     // 4096 bf16

  precompute_kernel<<<NND/4 + 1, 256, 0, stream>>>(
      nf, w_gate, b_gate, ln_b, w_out, b_out, w_db, w_edge, ln_g,
      g1, g2, bias2, wdbF, wedF, woF);
  fused_main_kernel<<<NND, 256, 0, stream>>>(
      trans, eidx, g1, g2, ef, b_edge, b_db, bias2,
      wdbF, wedF, woF, out);
}

// Round 12
// 30.964 us; speedup vs baseline: 1.3129x; 1.0716x over previous
//
#include <hip/hip_runtime.h>
#include <hip/hip_bf16.h>

#define NND 2000
#define KNB 16
#define CS 128
#define CZ 64
#define NE (NND*KNB)

typedef __attribute__((ext_vector_type(8))) short short8;
typedef __attribute__((ext_vector_type(4))) float f32x4;
typedef __attribute__((ext_vector_type(2))) unsigned int uint2v;
typedef __attribute__((ext_vector_type(4))) unsigned int uint4v;

// hardware bf16 convert (compiler emits v_cvt_pk_bf16_f32; RNE)
__device__ __forceinline__ unsigned int pk2(float a, float b) {
  __hip_bfloat162 h = __float22bfloat162_rn(make_float2(a, b));
  unsigned int u;
  __builtin_memcpy(&u, &h, 4);
  return u;
}
__device__ __forceinline__ unsigned short bfc(float f) {
  __hip_bfloat16 h = __float2bfloat16(f);
  unsigned short u;
  __builtin_memcpy(&u, &h, 2);
  return u;
}

__device__ __forceinline__ float fexp2(float x) {
#if __has_builtin(__builtin_amdgcn_exp2f)
  return __builtin_amdgcn_exp2f(x);
#else
  return __expf(0.6931471805599453f * x);
#endif
}

// ---------------------------------------------------------------------------
// Precompute:
//   blocks [0,500): per-node gate factors E1 = exp(-(nf@wg1 + b_gate)),
//     E2 = exp(-(nf@wg2)). w_gate staged once per block into 64KB LDS.
//     Gate in fused becomes sigmoid(z1+z2) = 1/(1 + E1*E2) -- no exp there.
//   block 500: wave0 bias2; wave1 wdbF; wave2 wedF; wave3 woF (bf16 frags).
// ---------------------------------------------------------------------------
__global__ __launch_bounds__(256) void precompute_kernel(
    const float* __restrict__ nf,
    const float* __restrict__ w_gate, const float* __restrict__ b_gate,
    const float* __restrict__ ln_b, const float* __restrict__ w_out,
    const float* __restrict__ b_out,
    const float* __restrict__ w_db, const float* __restrict__ w_edge,
    const float* __restrict__ ln_g,
    float* __restrict__ g1, float* __restrict__ g2, float* __restrict__ bias2,
    unsigned short* __restrict__ wdbF, unsigned short* __restrict__ wedF,
    unsigned short* __restrict__ woF)
{
  __shared__ float wl[2*CS][CZ];        // 64 KB: w_gate staged per block
  const int p = threadIdx.x;
  const int lane = p & 63;
  const int wv   = p >> 6;
  const int b    = blockIdx.x;
  if (b < NND/4) {
    #pragma unroll
    for (int t = 0; t < 16; ++t) {
      const int e = (p + 256*t) * 4;
      const f32x4 x = *(const f32x4*)&w_gate[e];
      *(f32x4*)&wl[e >> 6][e & 63] = x;
    }
    __syncthreads();

    const int v = b*4 + wv;
    const float* nrow = nf + v*CS;
    float a10=0.f,a11=0.f,a12=0.f,a13=0.f;
    float a20=0.f,a21=0.f,a22=0.f,a23=0.f;
    #pragma unroll
    for (int cc = 0; cc < CS; cc += 4) {
      const f32x4 x = *(const f32x4*)&nrow[cc];
      a10 = fmaf(x[0], wl[cc+0][lane], a10);
      a11 = fmaf(x[1], wl[cc+1][lane], a11);
      a12 = fmaf(x[2], wl[cc+2][lane], a12);
      a13 = fmaf(x[3], wl[cc+3][lane], a13);
      a20 = fmaf(x[0], wl[CS+cc+0][lane], a20);
      a21 = fmaf(x[1], wl[CS+cc+1][lane], a21);
      a22 = fmaf(x[2], wl[CS+cc+2][lane], a22);
      a23 = fmaf(x[3], wl[CS+cc+3][lane], a23);
    }
    const float a1 = b_gate[lane] + ((a10+a11)+(a12+a13));
    const float a2 = (a20+a21)+(a22+a23);
    // E1 = exp(-z1), E2 = exp(-z2)  (exp2 with log2e folded)
    g1[v*CZ + lane] = fexp2(a1 * -1.4426950408889634f);
    g2[v*CZ + lane] = fexp2(a2 * -1.4426950408889634f);
  } else {
    if (wv == 0) {
      float a = b_out[lane];
      #pragma unroll
      for (int cc = 0; cc < CZ; ++cc)
        a = fmaf(ln_b[cc], w_out[cc*CZ + lane], a);
      bias2[lane] = a;
    } else if (wv == 1) {
      for (int e = lane; e < 4096; e += 64) {
        const int entry = e >> 3, t = e & 7;
        const int l2 = entry & 63, sn = entry >> 6;
        const int s = sn >> 2, nt = sn & 3;
        const int q2 = l2 >> 4, c2 = l2 & 15;
        wdbF[e] = bfc(w_db[(32*s + 8*q2 + t)*CZ + 16*nt + c2]);
      }
    } else if (wv == 2) {
      for (int e = lane; e < 4096; e += 64) {
        const int entry = e >> 3, t = e & 7;
        const int p2 = entry & 255, s = entry >> 8;
        const int q2 = (p2 >> 4) & 3, c2 = p2 & 15;
        wedF[e] = bfc(w_edge[(32*s + 8*q2 + t)*CZ + 16*(p2 >> 6) + c2]);
      }
    } else {
      for (int e = lane; e < 4096; e += 64) {
        const int entry = e >> 3, t = e & 7;
        const int p2 = entry & 255, s = entry >> 8;
        const int q2 = (p2 >> 4) & 3, c2 = p2 & 15;
        const int k = 32*s + 8*q2 + t;
        woF[e] = bfc(w_out[k*CZ + 16*(p2 >> 6) + c2] * ln_g[k]);
      }
    }
  }
}

// ---------------------------------------------------------------------------
// Fused main kernel: r11 structure (one block of 4 waves per node, 3
// barriers, front-loaded traffic), with: gate = rcp(1 + E1*E2) (no exp2),
// b_db folded into MFMA C-init, all bf16 cvts via v_cvt_pk_bf16_f32.
// ---------------------------------------------------------------------------
__global__ __launch_bounds__(256, 4) void fused_main_kernel(
    const float* __restrict__ trans, const int* __restrict__ eidx,
    const float* __restrict__ g1, const float* __restrict__ g2,
    const float* __restrict__ ef, const float* __restrict__ b_edge,
    const float* __restrict__ b_db, const float* __restrict__ bias2,
    const unsigned short* __restrict__ wdbF,
    const unsigned short* __restrict__ wedF,
    const unsigned short* __restrict__ woF,
    float* __restrict__ out)
{
  __shared__ float G1l[KNB][68];
  __shared__ float G2l[KNB][68];
  __shared__ float kfl[KNB][68];
  __shared__ unsigned short xh[KNB][72];     // xhat bf16 (also ef-tile buffer)

  const int n = blockIdx.x;
  const int p = threadIdx.x;
  const int w = p >> 6;
  const int l = p & 63;
  const int q = l >> 4;
  const int c = l & 15;
  const int r16 = p >> 4, c4 = (p & 15) * 4;

  // ---- front-loaded global traffic --------------------------------------
  const int sr = eidx[n*KNB + r16];
  const int sc = eidx[n*KNB + c];
  int sj[4];
  #pragma unroll
  for (int m = 0; m < 4; ++m) sj[m] = eidx[n*KNB + 4*w + m];

  const f32x4 g1row = *(const f32x4*)&g1[sr*CZ + c4];
  const f32x4 g2row = *(const f32x4*)&g2[sr*CZ + c4];
  const f32x4 efrow = *(const f32x4*)&ef[(n*KNB + r16)*CZ + c4];

  const float tc0 = trans[sc*3+0], tc1 = trans[sc*3+1], tc2 = trans[sc*3+2];
  float tj[4][3];
  #pragma unroll
  for (int m = 0; m < 4; ++m) {
    tj[m][0] = trans[sj[m]*3+0];
    tj[m][1] = trans[sj[m]*3+1];
    tj[m][2] = trans[sj[m]*3+2];
  }

  short8 wed[2];
  #pragma unroll
  for (int s = 0; s < 2; ++s)
    wed[s] = *(const short8*)&wedF[(s*256 + p)*8];
  short8 bcur[2];
  #pragma unroll
  for (int s = 0; s < 2; ++s)
    bcur[s] = *(const short8*)&wdbF[(s*4*64 + l)*8];

  const float be = b_edge[16*w + c];
  const float bo = bias2[16*w + c];
  float bdb[4];
  #pragma unroll
  for (int nt = 0; nt < 4; ++nt) bdb[nt] = b_db[16*nt + c];

  // ---- register-only compute while loads land ---------------------------
  const float STEP = 1.2201878439258035f;
  float dsc[4];
  #pragma unroll
  for (int m = 0; m < 4; ++m) {
    const float dx = tc0 - tj[m][0] + 1e-8f;
    const float dy = tc1 - tj[m][1] + 1e-8f;
    const float dz = tc2 - tj[m][2] + 1e-8f;
    dsc[m] = sqrtf(fmaf(dx,dx, fmaf(dy,dy, dz*dz))) * 3.8435917081166394f;
  }
  const float qoff = (float)(8*q) * STEP;

  // rbf A-frags via packed cvt: af[s][m], row i=c, k = 32s+8q+t
  short8 af[2][4];
  #pragma unroll
  for (int s = 0; s < 2; ++s) {
    const float soff = qoff + (float)(32*s) * STEP;
    #pragma unroll
    for (int m = 0; m < 4; ++m) {
      const float bse = dsc[m] - soff;
      uint4v u;
      #pragma unroll
      for (int t = 0; t < 4; ++t) {
        const float ua = fmaf(-STEP, (float)(2*t),   bse);
        const float ub = fmaf(-STEP, (float)(2*t+1), bse);
        u[t] = pk2(fexp2(-ua*ua), fexp2(-ub*ub));
      }
      short8 v;
      __builtin_memcpy(&v, &u, 16);
      af[s][m] = v;
    }
  }

  { // stage ef tile bf16 (into xh) + G rows (register -> LDS)
    uint2v pk;
    pk[0] = pk2(efrow[0], efrow[1]);
    pk[1] = pk2(efrow[2], efrow[3]);
    *(uint2v*)&xh[r16][c4] = pk;
    *(f32x4*)&G1l[r16][c4] = g1row;
    *(f32x4*)&G2l[r16][c4] = g2row;
  }
  __syncthreads();   // b1: ef tile (in xh), G1l, G2l visible

  { // MFMA0: kf tile; wave w owns cols 16w..16w+15
    f32x4 ak = {};
    #pragma unroll
    for (int s = 0; s < 2; ++s) {
      const short8 a0 = *(const short8*)&xh[c][q*8 + 32*s];
      ak = __builtin_amdgcn_mfma_f32_16x16x32_bf16(a0, wed[s], ak, 0, 0, 0);
    }
    #pragma unroll
    for (int r = 0; r < 4; ++r)
      kfl[4*q + r][16*w + c] = ak[r] + be;
  }
  __syncthreads();   // b2: kfl visible (xh free again)

  // ---- per-nt fused MFMA1 + gate + i-reduce -----------------------------
  float upd[4][4];   // [m][nt]
  #pragma unroll
  for (int nt = 0; nt < 4; ++nt) {
    short8 bnext[2];
    if (nt < 3) {
      #pragma unroll
      for (int s = 0; s < 2; ++s)
        bnext[s] = *(const short8*)&wdbF[((s*4 + nt+1)*64 + l)*8];
    }
    float e1v[4], kfv[4];
    #pragma unroll
    for (int r = 0; r < 4; ++r) {
      e1v[r] = G1l[4*q + r][16*nt + c];   // E1[i,h]
      kfv[r] = kfl[4*q + r][16*nt + c];
    }
    const float bdbn = bdb[nt];
    f32x4 acc[4];
    #pragma unroll
    for (int m = 0; m < 4; ++m) acc[m] = (f32x4){bdbn, bdbn, bdbn, bdbn};
    #pragma unroll
    for (int s = 0; s < 2; ++s)
      #pragma unroll
      for (int m = 0; m < 4; ++m)
        acc[m] = __builtin_amdgcn_mfma_f32_16x16x32_bf16(af[s][m], bcur[s], acc[m], 0, 0, 0);

    #pragma unroll
    for (int m = 0; m < 4; ++m) {
      const float e2m = G2l[4*w + m][16*nt + c];   // E2[j,h]
      float ss = 0.f;
      #pragma unroll
      for (int r = 0; r < 4; ++r) {
        // sigmoid(z1+z2) = 1/(1 + e^-z1 * e^-z2), exponentials precomputed
        const float gate = __builtin_amdgcn_rcpf(fmaf(e1v[r], e2m, 1.0f));
        ss = fmaf(gate * acc[m][r], kfv[r], ss);
      }
      ss += __shfl_xor(ss, 16);
      ss += __shfl_xor(ss, 32);
      upd[m][nt] = ss;
    }
    if (nt < 3) { bcur[0] = bnext[0]; bcur[1] = bnext[1]; }
  }

  // proj B-frags (hide under LN)
  short8 wb[2];
  #pragma unroll
  for (int s = 0; s < 2; ++s)
    wb[s] = *(const short8*)&woF[(s*256 + p)*8];

  // ---- LayerNorm: q-group q owns row j = 4w+q ---------------------------
  {
    float v[4];
    #pragma unroll
    for (int nt = 0; nt < 4; ++nt)
      v[nt] = (q == 0) ? upd[0][nt] : (q == 1) ? upd[1][nt]
            : (q == 2) ? upd[2][nt] : upd[3][nt];
    float s1 = (v[0] + v[1]) + (v[2] + v[3]);
    float s2 = fmaf(v[0],v[0], fmaf(v[1],v[1], fmaf(v[2],v[2], v[3]*v[3])));
    #pragma unroll
    for (int mk = 1; mk <= 8; mk <<= 1) {
      s1 += __shfl_xor(s1, mk);
      s2 += __shfl_xor(s2, mk);
    }
    const float mean = s1 * 0.015625f;
    const float var  = fmaf(s2, 0.015625f, -mean*mean);
    const float rstd = rsqrtf(var + 1e-5f);
    #pragma unroll
    for (int nt = 0; nt < 4; ++nt)
      xh[4*w + q][16*nt + c] = bfc((v[nt] - mean) * rstd);
  }
  __syncthreads();   // b3: xh visible

  // ---- MFMA2: out = xhat @ (ln_g*w_out) + bias2 -------------------------
  f32x4 acc2 = {};
  #pragma unroll
  for (int s = 0; s < 2; ++s) {
    const short8 a2f = *(const short8*)&xh[c][q*8 + 32*s];
    acc2 = __builtin_amdgcn_mfma_f32_16x16x32_bf16(a2f, wb[s], acc2, 0, 0, 0);
  }
  #pragma unroll
  for (int r = 0; r < 4; ++r)
    out[(n*KNB + 4*q + r)*CZ + 16*w + c] = acc2[r] + bo;
}

extern "C" void kernel_launch(void* const* d_in, const int* in_sizes, int n_in,
                              void* d_out, int out_size, void* d_ws, size_t ws_size,
                              hipStream_t stream)
{
  const float* nf     = (const float*)d_in[0];
  const float* trans  = (const float*)d_in[1];
  const float* ef     = (const float*)d_in[2];
  const int*   eidx   = (const int*)d_in[3];
  const float* w_gate = (const float*)d_in[4];
  const float* b_gate = (const float*)d_in[5];
  const float* w_db   = (const float*)d_in[6];
  const float* b_db   = (const float*)d_in[7];
  const float* w_edge = (const float*)d_in[8];
  const float* b_edge = (const float*)d_in[9];
  const float* ln_g   = (const float*)d_in[10];
  const float* ln_b   = (const float*)d_in[11];
  const float* w_out  = (const float*)d_in[12];
  const float* b_out  = (const float*)d_in[13];
  float* out = (float*)d_out;

  float* g1    = (float*)d_ws;                            // E1 [2000][64] f32
  float* g2    = g1 + NND*CZ;                             // E2 [2000][64] f32
  float* bias2 = g2 + NND*CZ;                             // [64] f32
  unsigned short* wdbF = (unsigned short*)(bias2 + CZ);   // 4096 bf16
  unsigned short* wedF = wdbF + 4096;                     // 4096 bf16
  unsigned short* woF  = wedF + 4096;                     // 4096 bf16

  precompute_kernel<<<NND/4 + 1, 256, 0, stream>>>(
      nf, w_gate, b_gate, ln_b, w_out, b_out, w_db, w_edge, ln_g,
      g1, g2, bias2, wdbF, wedF, woF);
  fused_main_kernel<<<NND, 256, 0, stream>>>(
      trans, eidx, g1, g2, ef, b_edge, b_db, bias2,
      wdbF, wedF, woF, out);
}